// Round 13
// baseline (265.591 us; speedup 1.0000x reference)
//
#include <hip/hip_runtime.h>
#include <math.h>

typedef float f32x4 __attribute__((ext_vector_type(4)));
typedef __bf16 bf16x8 __attribute__((ext_vector_type(8)));

#define MFMA16(a, b, c) __builtin_amdgcn_mfma_f32_16x16x32_bf16((a), (b), (c), 0, 0, 0)

constexpr int Bsz = 2, Nseq = 2048, Dm = 1024, Hh = 16, HDim = 64, F3 = 192;
constexpr int Mrows = Bsz * Nseq;   // 4096
constexpr int NC = Hh * F3;         // 3072 output cols
constexpr float QSCALE = 0.125f * 1.4426950408889634f;

__device__ inline void load_lds16(const void* g, void* l) {
    __builtin_amdgcn_global_load_lds((const __attribute__((address_space(1))) void*)g,
                                     (__attribute__((address_space(3))) void*)l, 16, 0, 0);
}

// ---------------- kernel 0: x fp32 -> bf16 ----------------
__global__ __launch_bounds__(256) void conv_x_kernel(const float* __restrict__ x,
                                                     __bf16* __restrict__ xb) {
    int i = blockIdx.x * 256 + threadIdx.x;
    const float4* xv = reinterpret_cast<const float4*>(x);
    float4 a = xv[2 * i];
    float4 b = xv[2 * i + 1];
    bf16x8 o = {(__bf16)a.x, (__bf16)a.y, (__bf16)a.z, (__bf16)a.w,
                (__bf16)b.x, (__bf16)b.y, (__bf16)b.z, (__bf16)b.w};
    *reinterpret_cast<bf16x8*>(xb + 8 * i) = o;
}

// ---------------- kernel 1: W fp32 [h][d][c] -> bf16 transposed [h][c][d] ----------------
__global__ __launch_bounds__(256) void conv_w_kernel(const float* __restrict__ w,
                                                     __bf16* __restrict__ wt) {
    __shared__ __bf16 tile[32][66];
    int h = blockIdx.z, d0 = blockIdx.x * 32, c0 = blockIdx.y * 64;
    for (int i = threadIdx.x; i < 32 * 64; i += 256) {
        int di = i >> 6, cj = i & 63;
        tile[di][cj] = (__bf16)w[(size_t)(h * Dm + d0 + di) * F3 + c0 + cj];
    }
    __syncthreads();
    for (int i = threadIdx.x; i < 32 * 64; i += 256) {
        int ci = i >> 5, dj = i & 31;
        wt[(size_t)(h * F3 + c0 + ci) * Dm + d0 + dj] = tile[dj][ci];
    }
}

// ---------------- kernel 2a: proj as m97-style 128x128 LDS-staged GEMM ----------------
__global__ __launch_bounds__(256) void gemm_proj(const __bf16* __restrict__ xb,
                                                 const __bf16* __restrict__ wt,
                                                 const float* __restrict__ bias,
                                                 __bf16* __restrict__ kbuf,
                                                 __bf16* __restrict__ qbuf,
                                                 __bf16* __restrict__ vt) {
    __shared__ __align__(16) __bf16 Ab[128 * 64];
    __shared__ __align__(16) __bf16 Bb[128 * 64];
    int wave = threadIdx.x >> 6, lane = threadIdx.x & 63;
    int col = lane & 15, quad = lane >> 4;
    int wm = wave & 1, wn = wave >> 1;
    int r0 = blockIdx.x * 128, n0 = blockIdx.y * 128;

    f32x4 acc[4][4] = {};

    for (int kt = 0; kt < Dm; kt += 64) {
        __syncthreads();
#pragma unroll
        for (int it = 0; it < 4; it++) {
            int row_t = it * 32 + wave * 8 + (lane >> 3);
            int jg = (lane & 7) ^ (row_t & 7);
            load_lds16(xb + (size_t)(r0 + row_t) * Dm + kt + jg * 8,
                       Ab + it * 2048 + wave * 512);
            load_lds16(wt + (size_t)(n0 + row_t) * Dm + kt + jg * 8,
                       Bb + it * 2048 + wave * 512);
        }
        __syncthreads();

#pragma unroll
        for (int ks = 0; ks < 2; ks++) {
            int cq = ks * 4 + quad;
            bf16x8 af[4], bfr[4];
#pragma unroll
            for (int mt = 0; mt < 4; mt++) {
                int row = wm * 64 + mt * 16 + col;
                af[mt] = *reinterpret_cast<const bf16x8*>(Ab + row * 64 + (cq ^ (row & 7)) * 8);
            }
#pragma unroll
            for (int nt = 0; nt < 4; nt++) {
                int row = wn * 64 + nt * 16 + col;
                bfr[nt] = *reinterpret_cast<const bf16x8*>(Bb + row * 64 + (cq ^ (row & 7)) * 8);
            }
#pragma unroll
            for (int mt = 0; mt < 4; mt++)
#pragma unroll
                for (int nt = 0; nt < 4; nt++)
                    acc[mt][nt] = MFMA16(af[mt], bfr[nt], acc[mt][nt]);
        }
    }

#pragma unroll
    for (int nt = 0; nt < 4; nt++) {
        int g = n0 + wn * 64 + nt * 16 + col;
        int h = g / F3, c = g - h * F3;
        float bv = bias[g];
        bool isq = (c >= 64 && c < 128), isv = (c >= 128);
        int cd = c & 63;
#pragma unroll
        for (int mt = 0; mt < 4; mt++) {
#pragma unroll
            for (int rg = 0; rg < 4; rg++) {
                int r = r0 + wm * 64 + mt * 16 + quad * 4 + rg;
                int b = r >> 11, n = r & (Nseq - 1);
                float v = acc[mt][nt][rg] + bv;
                if (isq) v *= QSCALE;
                size_t bh = (size_t)(b * Hh + h);
                if (isv) vt[(bh * HDim + cd) * Nseq + n] = (__bf16)v;
                else ((isq) ? qbuf : kbuf)[(bh * Nseq + n) * HDim + cd] = (__bf16)v;
            }
        }
    }
}

// ---------------- kernel 2b: fallback proj if ws too small ----------------
__global__ __launch_bounds__(256) void proj_small(const float* __restrict__ x,
                                                  const __bf16* __restrict__ wt,
                                                  const float* __restrict__ bias,
                                                  __bf16* __restrict__ kbuf,
                                                  __bf16* __restrict__ qbuf,
                                                  __bf16* __restrict__ vt) {
    int h = blockIdx.y;
    int wave = threadIdx.x >> 6, lane = threadIdx.x & 63;
    int col = lane & 15, quad = lane >> 4;
    int r0 = blockIdx.x * 128 + wave * 32;

    f32x4 acc[12][2] = {};
    const float* xr0 = x + (size_t)(r0 + col) * Dm + quad * 8;
    const float* xr1 = xr0 + 16 * Dm;
    const __bf16* wbase = wt + (size_t)(h * F3 + col) * Dm + quad * 8;

    for (int k0 = 0; k0 < Dm; k0 += 32) {
        float4 a0lo = *reinterpret_cast<const float4*>(xr0 + k0);
        float4 a0hi = *reinterpret_cast<const float4*>(xr0 + k0 + 4);
        float4 a1lo = *reinterpret_cast<const float4*>(xr1 + k0);
        float4 a1hi = *reinterpret_cast<const float4*>(xr1 + k0 + 4);
        bf16x8 a0 = {(__bf16)a0lo.x, (__bf16)a0lo.y, (__bf16)a0lo.z, (__bf16)a0lo.w,
                     (__bf16)a0hi.x, (__bf16)a0hi.y, (__bf16)a0hi.z, (__bf16)a0hi.w};
        bf16x8 a1 = {(__bf16)a1lo.x, (__bf16)a1lo.y, (__bf16)a1lo.z, (__bf16)a1lo.w,
                     (__bf16)a1hi.x, (__bf16)a1hi.y, (__bf16)a1hi.z, (__bf16)a1hi.w};
#pragma unroll
        for (int ct = 0; ct < 12; ct++) {
            bf16x8 bf = *reinterpret_cast<const bf16x8*>(wbase + ct * 16 * Dm + k0);
            acc[ct][0] = MFMA16(a0, bf, acc[ct][0]);
            acc[ct][1] = MFMA16(a1, bf, acc[ct][1]);
        }
    }
#pragma unroll
    for (int ct = 0; ct < 12; ct++) {
        int c = ct * 16 + col;
        float bv = bias[h * F3 + c];
        int cd = c & 63;
        bool isq = (c >= 64 && c < 128), isv = (c >= 128);
#pragma unroll
        for (int rt = 0; rt < 2; rt++) {
#pragma unroll
            for (int rg = 0; rg < 4; rg++) {
                int r = r0 + rt * 16 + quad * 4 + rg;
                int b = r >> 11, n = r & (Nseq - 1);
                float v = acc[ct][rt][rg] + bv;
                if (isq) v *= QSCALE;
                size_t bh = (size_t)(b * Hh + h);
                if (isv) vt[(bh * HDim + cd) * Nseq + n] = (__bf16)v;
                else ((isq) ? qbuf : kbuf)[(bh * Nseq + n) * HDim + cd] = (__bf16)v;
            }
        }
    }
}

// ---------------- kernel 3: causal flash attention, split-K 1024-thread blocks ----------------
// grid (16, Bsz*Hh), block 1024 (16 waves), 2 blocks/CU = 32 waves/CU.
// Waves 0-7: paired tiles (p / 31-p) x 16q, keys [0,H). Waves 8-15: same tiles,
// keys [H,kend). H = (kend/2) rounded to 64. No-max softmax => partials (o,lsum)
// are purely additive; combined through padded LDS at the end.
__global__ __launch_bounds__(1024, 8) void attn_kernel(const __bf16* __restrict__ qbuf,
                                                       const __bf16* __restrict__ kbuf,
                                                       const __bf16* __restrict__ vt,
                                                       float* __restrict__ out) {
    __shared__ __align__(16) __bf16 plds[16][16][72];  // per-wave P tile
    __shared__ float comb[8][64][21];                  // stride 21: conflict-free
    int bh = blockIdx.y;
    int b = bh >> 4, h = bh & 15;
    int wave = threadIdx.x >> 6, lane = threadIdx.x & 63;
    int col = lane & 15, quad = lane >> 4;
    int pair = blockIdx.x;
    int wlo = wave & 7;
    int tile = (wlo < 4) ? pair : (31 - pair);
    int q0 = tile * 64 + (wlo & 3) * 16;
    bool upper = wave >= 8;

    const __bf16* qbase = qbuf + (size_t)bh * Nseq * HDim;
    const __bf16* kbase = kbuf + (size_t)bh * Nseq * HDim;
    const __bf16* vbase = vt + (size_t)bh * HDim * Nseq;

    bf16x8 aq0 = *reinterpret_cast<const bf16x8*>(qbase + (q0 + col) * HDim + quad * 8);
    bf16x8 aq1 = *reinterpret_cast<const bf16x8*>(qbase + (q0 + col) * HDim + quad * 8 + 32);

    f32x4 o[4] = {};
    float lsum[4] = {0.f, 0.f, 0.f, 0.f};

    int sp = q0 & ~31;
    int kend = q0 + 16;
    int H = (kend >> 1) & ~63;           // lower/upper key split (multiple of 64, <= q0)
    int kb = upper ? H : 0;
    int mainend = upper ? q0 : H;        // main loop: kb + 64 <= mainend (all unmasked)

    // ---- main: unmasked 64-key iterations ----
    for (; kb + 64 <= mainend; kb += 64) {
        const __bf16* kr = kbase + (kb + col) * HDim + quad * 8;
        bf16x8 kf[4][2];
#pragma unroll
        for (int g = 0; g < 4; g++) {
            kf[g][0] = *reinterpret_cast<const bf16x8*>(kr + g * 16 * HDim);
            kf[g][1] = *reinterpret_cast<const bf16x8*>(kr + g * 16 * HDim + 32);
        }
        bf16x8 bv0[4], bv1[4];
#pragma unroll
        for (int nt = 0; nt < 4; nt++) {
            const __bf16* vp = vbase + (size_t)(nt * 16 + col) * Nseq + kb + quad * 8;
            bv0[nt] = *reinterpret_cast<const bf16x8*>(vp);
            bv1[nt] = *reinterpret_cast<const bf16x8*>(vp + 32);
        }
        f32x4 z = {};
        f32x4 s[4];
#pragma unroll
        for (int g = 0; g < 4; g++) {
            s[g] = MFMA16(aq0, kf[g][0], z);
            s[g] = MFMA16(aq1, kf[g][1], s[g]);
        }
#pragma unroll
        for (int g = 0; g < 4; g++) {
#pragma unroll
            for (int r = 0; r < 4; r++) {
                float p = exp2f(s[g][r]);
                lsum[r] += p;
                plds[wave][quad * 4 + r][col + 16 * g] = (__bf16)p;
            }
        }
        bf16x8 pa0 = *reinterpret_cast<const bf16x8*>(&plds[wave][col][quad * 8]);
        bf16x8 pa1 = *reinterpret_cast<const bf16x8*>(&plds[wave][col][32 + quad * 8]);
#pragma unroll
        for (int nt = 0; nt < 4; nt++) {
            o[nt] = MFMA16(pa0, bv0[nt], o[nt]);
            o[nt] = MFMA16(pa1, bv1[nt], o[nt]);
        }
    }
    // ---- tail (upper waves only): 32-key iterations, masked past sp ----
    if (upper) {
        for (; kb < kend; kb += 32) {
            const __bf16* kr = kbase + (kb + col) * HDim + quad * 8;
            bf16x8 c00 = *reinterpret_cast<const bf16x8*>(kr);
            bf16x8 c01 = *reinterpret_cast<const bf16x8*>(kr + 32);
            bf16x8 c10 = *reinterpret_cast<const bf16x8*>(kr + 16 * HDim);
            bf16x8 c11 = *reinterpret_cast<const bf16x8*>(kr + 16 * HDim + 32);
            f32x4 z = {};
            f32x4 s0 = MFMA16(aq0, c00, z);
            s0 = MFMA16(aq1, c01, s0);
            f32x4 s1 = MFMA16(aq0, c10, z);
            s1 = MFMA16(aq1, c11, s1);

            float p0[4], p1[4];
            if (kb >= sp) {
#pragma unroll
                for (int r = 0; r < 4; r++) {
                    int qi = q0 + quad * 4 + r;
                    p0[r] = (kb + col <= qi) ? exp2f(s0[r]) : 0.f;
                    p1[r] = (kb + 16 + col <= qi) ? exp2f(s1[r]) : 0.f;
                }
            } else {
#pragma unroll
                for (int r = 0; r < 4; r++) {
                    p0[r] = exp2f(s0[r]);
                    p1[r] = exp2f(s1[r]);
                }
            }
#pragma unroll
            for (int r = 0; r < 4; r++) {
                lsum[r] += p0[r] + p1[r];
                plds[wave][quad * 4 + r][col] = (__bf16)p0[r];
                plds[wave][quad * 4 + r][col + 16] = (__bf16)p1[r];
            }
            bf16x8 pa = *reinterpret_cast<const bf16x8*>(&plds[wave][col][quad * 8]);
#pragma unroll
            for (int nt = 0; nt < 4; nt++) {
                bf16x8 bv = *reinterpret_cast<const bf16x8*>(
                    vbase + (size_t)(nt * 16 + col) * Nseq + kb + quad * 8);
                o[nt] = MFMA16(pa, bv, o[nt]);
            }
        }
        // publish partials
#pragma unroll
        for (int nt = 0; nt < 4; nt++)
#pragma unroll
            for (int r = 0; r < 4; r++) comb[wave - 8][lane][nt * 4 + r] = o[nt][r];
#pragma unroll
        for (int r = 0; r < 4; r++) comb[wave - 8][lane][16 + r] = lsum[r];
    }
    __syncthreads();
    if (!upper) {
#pragma unroll
        for (int nt = 0; nt < 4; nt++)
#pragma unroll
            for (int r = 0; r < 4; r++) o[nt][r] += comb[wave][lane][nt * 4 + r];
#pragma unroll
        for (int r = 0; r < 4; r++) lsum[r] += comb[wave][lane][16 + r];

        float linv[4];
#pragma unroll
        for (int r = 0; r < 4; r++) {
            float s = lsum[r];
            s += __shfl_xor(s, 1);
            s += __shfl_xor(s, 2);
            s += __shfl_xor(s, 4);
            s += __shfl_xor(s, 8);
            linv[r] = 1.f / s;
        }
#pragma unroll
        for (int nt = 0; nt < 4; nt++) {
#pragma unroll
            for (int r = 0; r < 4; r++) {
                int qi = q0 + quad * 4 + r;
                out[((size_t)(b * Nseq + qi)) * Dm + h * HDim + nt * 16 + col] =
                    o[nt][r] * linv[r];
            }
        }
    }
}

extern "C" void kernel_launch(void* const* d_in, const int* in_sizes, int n_in,
                              void* d_out, int out_size, void* d_ws, size_t ws_size,
                              hipStream_t stream) {
    const float* x = nullptr;
    const float* w = nullptr;
    const float* bias = nullptr;
    for (int i = 0; i < n_in; i++) {
        if (in_sizes[i] == Mrows * Dm) x = (const float*)d_in[i];
        else if (in_sizes[i] == Hh * Dm * F3) w = (const float*)d_in[i];
        else if (in_sizes[i] == Hh * F3) bias = (const float*)d_in[i];
    }
    float* outp = (float*)d_out;

    // ws: wt 6 MB | kbuf 8 | qbuf 8 | vt 8 | xb 8 -> 38 MB
    char* ws = (char*)d_ws;
    __bf16* wt = (__bf16*)(ws);
    __bf16* kbuf = (__bf16*)(ws + 6291456);
    __bf16* qbuf = (__bf16*)(ws + 6291456 + 8388608);
    __bf16* vt = (__bf16*)(ws + 6291456 + 2 * 8388608);
    __bf16* xb = (__bf16*)(ws + 6291456 + 3 * 8388608);

    conv_w_kernel<<<dim3(Dm / 32, F3 / 64, Hh), 256, 0, stream>>>(w, wt);
    if (ws_size >= (size_t)(6291456 + 4 * 8388608)) {
        conv_x_kernel<<<Mrows * Dm / (8 * 256), 256, 0, stream>>>(x, xb);
        gemm_proj<<<dim3(Mrows / 128, NC / 128), 256, 0, stream>>>(xb, wt, bias, kbuf, qbuf, vt);
    } else {
        proj_small<<<dim3(Mrows / 128, Hh), 256, 0, stream>>>(x, wt, bias, kbuf, qbuf, vt);
    }
    attn_kernel<<<dim3(16, Bsz * Hh), 1024, 0, stream>>>(qbuf, kbuf, vt, outp);
}

// Round 14
// 169.573 us; speedup vs baseline: 1.5662x; 1.5662x over previous
//
#include <hip/hip_runtime.h>
#include <math.h>

typedef float f32x4 __attribute__((ext_vector_type(4)));
typedef __bf16 bf16x8 __attribute__((ext_vector_type(8)));

#define MFMA16(a, b, c) __builtin_amdgcn_mfma_f32_16x16x32_bf16((a), (b), (c), 0, 0, 0)

constexpr int Bsz = 2, Nseq = 2048, Dm = 1024, Hh = 16, HDim = 64, F3 = 192;
constexpr int Mrows = Bsz * Nseq;   // 4096
constexpr int NC = Hh * F3;         // 3072 output cols
constexpr float QSCALE = 0.125f * 1.4426950408889634f;

__device__ inline void load_lds16(const void* g, void* l) {
    __builtin_amdgcn_global_load_lds((const __attribute__((address_space(1))) void*)g,
                                     (__attribute__((address_space(3))) void*)l, 16, 0, 0);
}

// ---------------- kernel 0: x fp32 -> bf16 ----------------
__global__ __launch_bounds__(256) void conv_x_kernel(const float* __restrict__ x,
                                                     __bf16* __restrict__ xb) {
    int i = blockIdx.x * 256 + threadIdx.x;
    const float4* xv = reinterpret_cast<const float4*>(x);
    float4 a = xv[2 * i];
    float4 b = xv[2 * i + 1];
    bf16x8 o = {(__bf16)a.x, (__bf16)a.y, (__bf16)a.z, (__bf16)a.w,
                (__bf16)b.x, (__bf16)b.y, (__bf16)b.z, (__bf16)b.w};
    *reinterpret_cast<bf16x8*>(xb + 8 * i) = o;
}

// ---------------- kernel 1: W fp32 [h][d][c] -> bf16 transposed [h][c][d] ----------------
__global__ __launch_bounds__(256) void conv_w_kernel(const float* __restrict__ w,
                                                     __bf16* __restrict__ wt) {
    __shared__ __bf16 tile[32][66];
    int h = blockIdx.z, d0 = blockIdx.x * 32, c0 = blockIdx.y * 64;
    for (int i = threadIdx.x; i < 32 * 64; i += 256) {
        int di = i >> 6, cj = i & 63;
        tile[di][cj] = (__bf16)w[(size_t)(h * Dm + d0 + di) * F3 + c0 + cj];
    }
    __syncthreads();
    for (int i = threadIdx.x; i < 32 * 64; i += 256) {
        int ci = i >> 5, dj = i & 31;
        wt[(size_t)(h * F3 + c0 + ci) * Dm + d0 + dj] = tile[dj][ci];
    }
}

// ---------------- kernel 2a: proj as m97-style 128x128 LDS-staged GEMM ----------------
__global__ __launch_bounds__(256) void gemm_proj(const __bf16* __restrict__ xb,
                                                 const __bf16* __restrict__ wt,
                                                 const float* __restrict__ bias,
                                                 __bf16* __restrict__ kbuf,
                                                 __bf16* __restrict__ qbuf,
                                                 __bf16* __restrict__ vt) {
    __shared__ __align__(16) __bf16 Ab[128 * 64];
    __shared__ __align__(16) __bf16 Bb[128 * 64];
    int wave = threadIdx.x >> 6, lane = threadIdx.x & 63;
    int col = lane & 15, quad = lane >> 4;
    int wm = wave & 1, wn = wave >> 1;
    int r0 = blockIdx.x * 128, n0 = blockIdx.y * 128;

    f32x4 acc[4][4] = {};

    for (int kt = 0; kt < Dm; kt += 64) {
        __syncthreads();
#pragma unroll
        for (int it = 0; it < 4; it++) {
            int row_t = it * 32 + wave * 8 + (lane >> 3);
            int jg = (lane & 7) ^ (row_t & 7);
            load_lds16(xb + (size_t)(r0 + row_t) * Dm + kt + jg * 8,
                       Ab + it * 2048 + wave * 512);
            load_lds16(wt + (size_t)(n0 + row_t) * Dm + kt + jg * 8,
                       Bb + it * 2048 + wave * 512);
        }
        __syncthreads();

#pragma unroll
        for (int ks = 0; ks < 2; ks++) {
            int cq = ks * 4 + quad;
            bf16x8 af[4], bfr[4];
#pragma unroll
            for (int mt = 0; mt < 4; mt++) {
                int row = wm * 64 + mt * 16 + col;
                af[mt] = *reinterpret_cast<const bf16x8*>(Ab + row * 64 + (cq ^ (row & 7)) * 8);
            }
#pragma unroll
            for (int nt = 0; nt < 4; nt++) {
                int row = wn * 64 + nt * 16 + col;
                bfr[nt] = *reinterpret_cast<const bf16x8*>(Bb + row * 64 + (cq ^ (row & 7)) * 8);
            }
#pragma unroll
            for (int mt = 0; mt < 4; mt++)
#pragma unroll
                for (int nt = 0; nt < 4; nt++)
                    acc[mt][nt] = MFMA16(af[mt], bfr[nt], acc[mt][nt]);
        }
    }

#pragma unroll
    for (int nt = 0; nt < 4; nt++) {
        int g = n0 + wn * 64 + nt * 16 + col;
        int h = g / F3, c = g - h * F3;
        float bv = bias[g];
        bool isq = (c >= 64 && c < 128), isv = (c >= 128);
        int cd = c & 63;
#pragma unroll
        for (int mt = 0; mt < 4; mt++) {
#pragma unroll
            for (int rg = 0; rg < 4; rg++) {
                int r = r0 + wm * 64 + mt * 16 + quad * 4 + rg;
                int b = r >> 11, n = r & (Nseq - 1);
                float v = acc[mt][nt][rg] + bv;
                if (isq) v *= QSCALE;
                size_t bh = (size_t)(b * Hh + h);
                if (isv) vt[(bh * HDim + cd) * Nseq + n] = (__bf16)v;
                else ((isq) ? qbuf : kbuf)[(bh * Nseq + n) * HDim + cd] = (__bf16)v;
            }
        }
    }
}

// ---------------- kernel 2b: fallback proj if ws too small ----------------
__global__ __launch_bounds__(256) void proj_small(const float* __restrict__ x,
                                                  const __bf16* __restrict__ wt,
                                                  const float* __restrict__ bias,
                                                  __bf16* __restrict__ kbuf,
                                                  __bf16* __restrict__ qbuf,
                                                  __bf16* __restrict__ vt) {
    int h = blockIdx.y;
    int wave = threadIdx.x >> 6, lane = threadIdx.x & 63;
    int col = lane & 15, quad = lane >> 4;
    int r0 = blockIdx.x * 128 + wave * 32;

    f32x4 acc[12][2] = {};
    const float* xr0 = x + (size_t)(r0 + col) * Dm + quad * 8;
    const float* xr1 = xr0 + 16 * Dm;
    const __bf16* wbase = wt + (size_t)(h * F3 + col) * Dm + quad * 8;

    for (int k0 = 0; k0 < Dm; k0 += 32) {
        float4 a0lo = *reinterpret_cast<const float4*>(xr0 + k0);
        float4 a0hi = *reinterpret_cast<const float4*>(xr0 + k0 + 4);
        float4 a1lo = *reinterpret_cast<const float4*>(xr1 + k0);
        float4 a1hi = *reinterpret_cast<const float4*>(xr1 + k0 + 4);
        bf16x8 a0 = {(__bf16)a0lo.x, (__bf16)a0lo.y, (__bf16)a0lo.z, (__bf16)a0lo.w,
                     (__bf16)a0hi.x, (__bf16)a0hi.y, (__bf16)a0hi.z, (__bf16)a0hi.w};
        bf16x8 a1 = {(__bf16)a1lo.x, (__bf16)a1lo.y, (__bf16)a1lo.z, (__bf16)a1lo.w,
                     (__bf16)a1hi.x, (__bf16)a1hi.y, (__bf16)a1hi.z, (__bf16)a1hi.w};
#pragma unroll
        for (int ct = 0; ct < 12; ct++) {
            bf16x8 bf = *reinterpret_cast<const bf16x8*>(wbase + ct * 16 * Dm + k0);
            acc[ct][0] = MFMA16(a0, bf, acc[ct][0]);
            acc[ct][1] = MFMA16(a1, bf, acc[ct][1]);
        }
    }
#pragma unroll
    for (int ct = 0; ct < 12; ct++) {
        int c = ct * 16 + col;
        float bv = bias[h * F3 + c];
        int cd = c & 63;
        bool isq = (c >= 64 && c < 128), isv = (c >= 128);
#pragma unroll
        for (int rt = 0; rt < 2; rt++) {
#pragma unroll
            for (int rg = 0; rg < 4; rg++) {
                int r = r0 + rt * 16 + quad * 4 + rg;
                int b = r >> 11, n = r & (Nseq - 1);
                float v = acc[ct][rt][rg] + bv;
                if (isq) v *= QSCALE;
                size_t bh = (size_t)(b * Hh + h);
                if (isv) vt[(bh * HDim + cd) * Nseq + n] = (__bf16)v;
                else ((isq) ? qbuf : kbuf)[(bh * Nseq + n) * HDim + cd] = (__bf16)v;
            }
        }
    }
}

// ---------------- kernel 3: flash attention with LDS-staged K/V tiles ----------------
// grid (bh=32, pair=16), block 512 (8 waves). Waves 0-3: q-tile p; 4-7: q-tile 31-p
// (compute-balanced). Loop over 64-key blocks to the max tile's range: all 512
// threads cooperatively stage K (8 KB) and V^T (8 KB) into LDS (one 16B
// global_load_lds each, XOR-swizzled chunks), then waves compute predicated.
// Removes the per-wave redundant K/V global streams (8x traffic cut) that made
// R12/R13 HBM-latency-bound.
__global__ __launch_bounds__(512) void attn_kernel(const __bf16* __restrict__ qbuf,
                                                   const __bf16* __restrict__ kbuf,
                                                   const __bf16* __restrict__ vt,
                                                   float* __restrict__ out) {
    __shared__ __align__(16) __bf16 Kb[64 * 64];       // [key][dim], swizzled chunks
    __shared__ __align__(16) __bf16 Vb[64 * 64];       // [dim][key], swizzled chunks
    __shared__ __align__(16) __bf16 plds[8][16][72];   // per-wave P tile, 2-way max
    int bh = blockIdx.x;
    int b = bh >> 4, h = bh & 15;
    int pair = blockIdx.y;
    int wave = threadIdx.x >> 6, lane = threadIdx.x & 63;
    int col = lane & 15, quad = lane >> 4;
    int tile = (wave < 4) ? pair : (31 - pair);
    int q0 = tile * 64 + (wave & 3) * 16;

    const __bf16* qbase = qbuf + (size_t)bh * Nseq * HDim;
    const __bf16* kbase = kbuf + (size_t)bh * Nseq * HDim;
    const __bf16* vbase = vt + (size_t)bh * HDim * Nseq;

    bf16x8 aq0 = *reinterpret_cast<const bf16x8*>(qbase + (q0 + col) * HDim + quad * 8);
    bf16x8 aq1 = *reinterpret_cast<const bf16x8*>(qbase + (q0 + col) * HDim + quad * 8 + 32);

    f32x4 o[4] = {};
    float lsum[4] = {0.f, 0.f, 0.f, 0.f};

    int mb = q0 & ~63;                  // the one masked 64-key block for this wave
    int loop_end = 2048 - 64 * pair;    // max kend over both tiles, rounded to 64

    // staging indices (thread-invariant across iterations)
    int srow = threadIdx.x >> 3;                      // key (K) / dim (V) row 0..63
    int schunk = (threadIdx.x & 7) ^ (srow & 7);      // swizzled 16B chunk
    const __bf16* ksrc0 = kbase + srow * HDim + schunk * 8;
    const __bf16* vsrc0 = vbase + (size_t)srow * Nseq + schunk * 8;
    __bf16* kdst = Kb + wave * 512;
    __bf16* vdst = Vb + wave * 512;

    // readback swizzle offsets
    int sw0 = ((quad ^ (col & 7)) * 8);
    int sw1 = (((quad + 4) ^ (col & 7)) * 8);

    for (int kb = 0; kb < loop_end; kb += 64) {
        __syncthreads();  // previous iteration's LDS reads complete
        load_lds16(ksrc0 + kb * HDim, kdst);
        load_lds16(vsrc0 + kb, vdst);
        __syncthreads();  // staging visible

        if (kb <= mb) {
            bool masked = (kb == mb);
            // QK^T from LDS K tile
            f32x4 z = {};
            f32x4 s[4];
#pragma unroll
            for (int g = 0; g < 4; g++) {
                const __bf16* krow = Kb + (col + 16 * g) * 64;
                bf16x8 k0 = *reinterpret_cast<const bf16x8*>(krow + sw0);
                bf16x8 k1 = *reinterpret_cast<const bf16x8*>(krow + sw1);
                s[g] = MFMA16(aq0, k0, z);
                s[g] = MFMA16(aq1, k1, s[g]);
            }
            // softmax (no-max) + P to LDS
            if (masked) {
#pragma unroll
                for (int g = 0; g < 4; g++) {
#pragma unroll
                    for (int r = 0; r < 4; r++) {
                        int qi = q0 + quad * 4 + r;
                        float p = (kb + col + 16 * g <= qi) ? exp2f(s[g][r]) : 0.f;
                        lsum[r] += p;
                        plds[wave][quad * 4 + r][col + 16 * g] = (__bf16)p;
                    }
                }
            } else {
#pragma unroll
                for (int g = 0; g < 4; g++) {
#pragma unroll
                    for (int r = 0; r < 4; r++) {
                        float p = exp2f(s[g][r]);
                        lsum[r] += p;
                        plds[wave][quad * 4 + r][col + 16 * g] = (__bf16)p;
                    }
                }
            }
            bf16x8 pa0 = *reinterpret_cast<const bf16x8*>(&plds[wave][col][quad * 8]);
            bf16x8 pa1 = *reinterpret_cast<const bf16x8*>(&plds[wave][col][32 + quad * 8]);
            // PV from LDS V tile
#pragma unroll
            for (int nt = 0; nt < 4; nt++) {
                const __bf16* vrow = Vb + (col + 16 * nt) * 64;
                bf16x8 v0 = *reinterpret_cast<const bf16x8*>(vrow + sw0);
                bf16x8 v1 = *reinterpret_cast<const bf16x8*>(vrow + sw1);
                o[nt] = MFMA16(pa0, v0, o[nt]);
                o[nt] = MFMA16(pa1, v1, o[nt]);
            }
        }
    }

    float linv[4];
#pragma unroll
    for (int r = 0; r < 4; r++) {
        float s = lsum[r];
        s += __shfl_xor(s, 1);
        s += __shfl_xor(s, 2);
        s += __shfl_xor(s, 4);
        s += __shfl_xor(s, 8);
        linv[r] = 1.f / s;
    }
#pragma unroll
    for (int nt = 0; nt < 4; nt++) {
#pragma unroll
        for (int r = 0; r < 4; r++) {
            int qi = q0 + quad * 4 + r;
            out[((size_t)(b * Nseq + qi)) * Dm + h * HDim + nt * 16 + col] = o[nt][r] * linv[r];
        }
    }
}

extern "C" void kernel_launch(void* const* d_in, const int* in_sizes, int n_in,
                              void* d_out, int out_size, void* d_ws, size_t ws_size,
                              hipStream_t stream) {
    const float* x = nullptr;
    const float* w = nullptr;
    const float* bias = nullptr;
    for (int i = 0; i < n_in; i++) {
        if (in_sizes[i] == Mrows * Dm) x = (const float*)d_in[i];
        else if (in_sizes[i] == Hh * Dm * F3) w = (const float*)d_in[i];
        else if (in_sizes[i] == Hh * F3) bias = (const float*)d_in[i];
    }
    float* outp = (float*)d_out;

    // ws: wt 6 MB | kbuf 8 | qbuf 8 | vt 8 | xb 8 -> 38 MB
    char* ws = (char*)d_ws;
    __bf16* wt = (__bf16*)(ws);
    __bf16* kbuf = (__bf16*)(ws + 6291456);
    __bf16* qbuf = (__bf16*)(ws + 6291456 + 8388608);
    __bf16* vt = (__bf16*)(ws + 6291456 + 2 * 8388608);
    __bf16* xb = (__bf16*)(ws + 6291456 + 3 * 8388608);

    conv_w_kernel<<<dim3(Dm / 32, F3 / 64, Hh), 256, 0, stream>>>(w, wt);
    if (ws_size >= (size_t)(6291456 + 4 * 8388608)) {
        conv_x_kernel<<<Mrows * Dm / (8 * 256), 256, 0, stream>>>(x, xb);
        gemm_proj<<<dim3(Mrows / 128, NC / 128), 256, 0, stream>>>(xb, wt, bias, kbuf, qbuf, vt);
    } else {
        proj_small<<<dim3(Mrows / 128, Hh), 256, 0, stream>>>(x, wt, bias, kbuf, qbuf, vt);
    }
    attn_kernel<<<dim3(32, 16), 512, 0, stream>>>(qbuf, kbuf, vt, outp);
}